// Round 1
// baseline (102.268 us; speedup 1.0000x reference)
//
#include <hip/hip_runtime.h>

// vol:  [B=8, D=64, H=128, W=128, C=2] f32
// flow: [B, D, H, W, 3] f32 (displacements)
// out:  [B, D, H, W, C] f32
//
// Trilinear sample with edge-clamp (fill_value=None semantics):
//   clipped = clip(grid + flow, 0, dim-1)
//   lo      = clip(floor(clipped), 0, dim-2)
//   w       = clipped - lo          (in [0,1])
//   out     = sum over 8 corners vol[lo+bits] * prod(w or 1-w)

__global__ __launch_bounds__(256) void st_warp_kernel(
    const float* __restrict__ vol,
    const float* __restrict__ flow,
    float* __restrict__ out,
    int total)  // total = B*D*H*W = 2^23
{
    const int stride = gridDim.x * blockDim.x;
    for (int idx = blockIdx.x * blockDim.x + threadIdx.x; idx < total; idx += stride) {
        // decompose: w = bits 0..6, h = bits 7..13, d = bits 14..19, b = bits 20..22
        const int w = idx & 127;
        const int h = (idx >> 7) & 127;
        const int d = (idx >> 14) & 63;
        const int b = idx >> 20;

        // flow is [...,3] interleaved: 3 coalesced-ish dword loads per lane
        const float* fp = flow + (size_t)idx * 3;
        float cd = (float)d + fp[0];
        float ch = (float)h + fp[1];
        float cw = (float)w + fp[2];

        // clamp to [0, dim-1]
        cd = fminf(fmaxf(cd, 0.0f), 63.0f);
        ch = fminf(fmaxf(ch, 0.0f), 127.0f);
        cw = fminf(fmaxf(cw, 0.0f), 127.0f);

        // lo = clip(floor, 0, dim-2); coords >= 0 so int-cast == floor
        int ld = (int)cd; ld = (ld > 62) ? 62 : ld;
        int lh = (int)ch; lh = (lh > 126) ? 126 : lh;
        int lw = (int)cw; lw = (lw > 126) ? 126 : lw;

        const float wd = cd - (float)ld;
        const float wh = ch - (float)lh;
        const float ww = cw - (float)lw;

        // per-batch volume base: b * D*H*W*C = b * 2^21 floats
        const float* vb = vol + ((size_t)b << 21);
        // element offset of corner (ld,lh,lw): d*2^15 + h*2^8 + w*2
        const int o = (ld << 15) + (lh << 8) + (lw << 1);

        // 8 corners, each a float2 (C=2 contiguous, 8B-aligned)
        const float2* p00 = (const float2*)(vb + o);                       // (ld  ,lh  ,lw / lw+1)
        const float2* p01 = (const float2*)(vb + o + (1 << 8));            // (ld  ,lh+1, *)
        const float2* p10 = (const float2*)(vb + o + (1 << 15));           // (ld+1,lh  , *)
        const float2* p11 = (const float2*)(vb + o + (1 << 15) + (1 << 8));// (ld+1,lh+1, *)

        const float2 v000 = p00[0], v001 = p00[1];
        const float2 v010 = p01[0], v011 = p01[1];
        const float2 v100 = p10[0], v101 = p10[1];
        const float2 v110 = p11[0], v111 = p11[1];

        const float wd0 = 1.0f - wd, wh0 = 1.0f - wh, ww0 = 1.0f - ww;
        const float w00 = wd0 * wh0;  // d-lo, h-lo
        const float w01 = wd0 * wh;   // d-lo, h-hi
        const float w10 = wd  * wh0;  // d-hi, h-lo
        const float w11 = wd  * wh;   // d-hi, h-hi

        const float ox = (v000.x * w00 + v010.x * w01 + v100.x * w10 + v110.x * w11) * ww0
                       + (v001.x * w00 + v011.x * w01 + v101.x * w10 + v111.x * w11) * ww;
        const float oy = (v000.y * w00 + v010.y * w01 + v100.y * w10 + v110.y * w11) * ww0
                       + (v001.y * w00 + v011.y * w01 + v101.y * w10 + v111.y * w11) * ww;

        // coalesced float2 store
        reinterpret_cast<float2*>(out)[idx] = make_float2(ox, oy);
    }
}

extern "C" void kernel_launch(void* const* d_in, const int* in_sizes, int n_in,
                              void* d_out, int out_size, void* d_ws, size_t ws_size,
                              hipStream_t stream) {
    const float* vol  = (const float*)d_in[0];
    const float* flow = (const float*)d_in[1];
    float* out = (float*)d_out;

    const int total = in_sizes[1] / 3;  // B*D*H*W = 8388608
    const int block = 256;
    const int grid  = 2048;             // 256 CU x 8 blocks/CU, grid-stride

    hipLaunchKernelGGL(st_warp_kernel, dim3(grid), dim3(block), 0, stream,
                       vol, flow, out, total);
}

// Round 3
// 97.296 us; speedup vs baseline: 1.0511x; 1.0511x over previous
//
#include <hip/hip_runtime.h>

// vol:  [B=8, D=64, H=128, W=128, C=2] f32
// flow: [B, D, H, W, 3] f32 (displacements)
// out:  [B, D, H, W, C] f32
//
// 4 consecutive W-voxels per thread:
//  - flow: 6 x float2 loads (48 B/lane, 8B-aligned guaranteed)
//  - 32 independent float2 gathers in flight (4x MLP vs 1-voxel/thread)
//  - out: 2 x float4 coalesced stores
// Straight-line per-voxel code (no private arrays -> no scratch risk).

__device__ __forceinline__ float2 trilerp(const float* __restrict__ vb,
                                          float cd, float ch, float cw) {
    // clamp to [0, dim-1]
    cd = fminf(fmaxf(cd, 0.0f), 63.0f);
    ch = fminf(fmaxf(ch, 0.0f), 127.0f);
    cw = fminf(fmaxf(cw, 0.0f), 127.0f);

    // lo = clip(floor, 0, dim-2); coords >= 0 so int-cast == floor
    int ld = (int)cd; ld = (ld > 62) ? 62 : ld;
    int lh = (int)ch; lh = (lh > 126) ? 126 : lh;
    int lw = (int)cw; lw = (lw > 126) ? 126 : lw;

    const float wd = cd - (float)ld;
    const float wh = ch - (float)lh;
    const float ww = cw - (float)lw;

    const int o = (ld << 15) + (lh << 8) + (lw << 1);
    const float2* p00 = (const float2*)(vb + o);                        // (ld  ,lh  )
    const float2* p01 = (const float2*)(vb + o + (1 << 8));             // (ld  ,lh+1)
    const float2* p10 = (const float2*)(vb + o + (1 << 15));            // (ld+1,lh  )
    const float2* p11 = (const float2*)(vb + o + (1 << 15) + (1 << 8)); // (ld+1,lh+1)

    const float2 v000 = p00[0], v001 = p00[1];
    const float2 v010 = p01[0], v011 = p01[1];
    const float2 v100 = p10[0], v101 = p10[1];
    const float2 v110 = p11[0], v111 = p11[1];

    const float wd0 = 1.0f - wd, wh0 = 1.0f - wh, ww0 = 1.0f - ww;
    const float w00 = wd0 * wh0;
    const float w01 = wd0 * wh;
    const float w10 = wd  * wh0;
    const float w11 = wd  * wh;

    float2 r;
    r.x = (v000.x * w00 + v010.x * w01 + v100.x * w10 + v110.x * w11) * ww0
        + (v001.x * w00 + v011.x * w01 + v101.x * w10 + v111.x * w11) * ww;
    r.y = (v000.y * w00 + v010.y * w01 + v100.y * w10 + v110.y * w11) * ww0
        + (v001.y * w00 + v011.y * w01 + v101.y * w10 + v111.y * w11) * ww;
    return r;
}

__global__ __launch_bounds__(256) void st_warp4_kernel(
    const float* __restrict__ vol,
    const float* __restrict__ flow,
    float* __restrict__ out,
    int ngroups)  // B*D*H*W/4 = 2^21
{
    const int g = blockIdx.x * blockDim.x + threadIdx.x;
    if (g >= ngroups) return;
    const int idx = g << 2;  // base voxel; w-base is mult of 4, never crosses a W-row

    const int w0 = idx & 127;
    const int h  = (idx >> 7) & 127;
    const int d  = (idx >> 14) & 63;
    const int b  = idx >> 20;

    // 12 flow floats for 4 voxels, as 6 x float2 (8B-aligned: byte off = g*48)
    const float2* fp = (const float2*)(flow + (size_t)idx * 3);
    const float2 q0 = fp[0];  // v0.d, v0.h
    const float2 q1 = fp[1];  // v0.w, v1.d
    const float2 q2 = fp[2];  // v1.h, v1.w
    const float2 q3 = fp[3];  // v2.d, v2.h
    const float2 q4 = fp[4];  // v2.w, v3.d
    const float2 q5 = fp[5];  // v3.h, v3.w

    const float fd_ = (float)d;
    const float fh_ = (float)h;
    const float* vb = vol + ((size_t)b << 21);  // batch base (2^21 floats)

    const float2 r0 = trilerp(vb, fd_ + q0.x, fh_ + q0.y, (float)(w0 + 0) + q1.x);
    const float2 r1 = trilerp(vb, fd_ + q1.y, fh_ + q2.x, (float)(w0 + 1) + q2.y);
    const float2 r2 = trilerp(vb, fd_ + q3.x, fh_ + q3.y, (float)(w0 + 2) + q4.x);
    const float2 r3 = trilerp(vb, fd_ + q4.y, fh_ + q5.x, (float)(w0 + 3) + q5.y);

    // 32 contiguous bytes per lane -> 2 x dwordx4 stores
    float4* o4 = reinterpret_cast<float4*>(out);
    o4[(size_t)g * 2]     = make_float4(r0.x, r0.y, r1.x, r1.y);
    o4[(size_t)g * 2 + 1] = make_float4(r2.x, r2.y, r3.x, r3.y);
}

extern "C" void kernel_launch(void* const* d_in, const int* in_sizes, int n_in,
                              void* d_out, int out_size, void* d_ws, size_t ws_size,
                              hipStream_t stream) {
    const float* vol  = (const float*)d_in[0];
    const float* flow = (const float*)d_in[1];
    float* out = (float*)d_out;

    const int total   = in_sizes[1] / 3;   // B*D*H*W = 8388608
    const int ngroups = total >> 2;        // 2097152
    const int block   = 256;
    const int grid    = (ngroups + block - 1) / block;  // 8192

    hipLaunchKernelGGL(st_warp4_kernel, dim3(grid), dim3(block), 0, stream,
                       vol, flow, out, ngroups);
}

// Round 5
// 93.693 us; speedup vs baseline: 1.0915x; 1.0385x over previous
//
#include <hip/hip_runtime.h>

// vol:  [B=8, D=64, H=128, W=128, C=2] f32
// flow: [B, D, H, W, 3] f32 (displacements)
// out:  [B, D, H, W, C] f32
//
// 4 consecutive W-voxels per thread, three-phase structure to maximize MLP:
//   phase 1: flow loads + all address/weight math (4 voxels)
//   phase 2: all 32 float2 gathers issued together
//   phase 3: weighted combine + 2 x float4 stores
// b and d are block-uniform (block = 1024 consecutive voxels) -> SGPR base.
// __launch_bounds__(256,4): allow ~128 VGPR so gathers stay in flight.

struct CornerInfo {
    int   o;   // element offset of (ld,lh,lw) corner within batch volume
    float wd, wh, ww;
};

__device__ __forceinline__ CornerInfo mkaddr(float cd, float ch, float cw) {
    cd = fminf(fmaxf(cd, 0.0f), 63.0f);
    ch = fminf(fmaxf(ch, 0.0f), 127.0f);
    cw = fminf(fmaxf(cw, 0.0f), 127.0f);
    int ld = (int)cd; ld = (ld > 62) ? 62 : ld;
    int lh = (int)ch; lh = (lh > 126) ? 126 : lh;
    int lw = (int)cw; lw = (lw > 126) ? 126 : lw;
    CornerInfo ci;
    ci.o  = (ld << 15) + (lh << 8) + (lw << 1);
    ci.wd = cd - (float)ld;
    ci.wh = ch - (float)lh;
    ci.ww = cw - (float)lw;
    return ci;
}

// 8 corner loads for one voxel: two d-planes, 4 imm-offset float2 loads each
#define GATHER8(P, base, o)                                          \
    const float2 P##_000 = *(const float2*)((base) + (o));           \
    const float2 P##_001 = *(const float2*)((base) + (o) + 2);       \
    const float2 P##_010 = *(const float2*)((base) + (o) + 256);     \
    const float2 P##_011 = *(const float2*)((base) + (o) + 258);     \
    const float2 P##_100 = *(const float2*)((base) + (o) + 32768);   \
    const float2 P##_101 = *(const float2*)((base) + (o) + 32770);   \
    const float2 P##_110 = *(const float2*)((base) + (o) + 33024);   \
    const float2 P##_111 = *(const float2*)((base) + (o) + 33026);

#define COMBINE(P, ci, res)                                                     \
    {                                                                           \
        const float wd0 = 1.0f - (ci).wd, wh0 = 1.0f - (ci).wh;                 \
        const float ww1 = (ci).ww, ww0 = 1.0f - ww1;                            \
        const float w00 = wd0 * wh0, w01 = wd0 * (ci).wh;                       \
        const float w10 = (ci).wd * wh0, w11 = (ci).wd * (ci).wh;               \
        (res).x = (P##_000.x * w00 + P##_010.x * w01 + P##_100.x * w10 + P##_110.x * w11) * ww0  \
                + (P##_001.x * w00 + P##_011.x * w01 + P##_101.x * w10 + P##_111.x * w11) * ww1; \
        (res).y = (P##_000.y * w00 + P##_010.y * w01 + P##_100.y * w10 + P##_110.y * w11) * ww0  \
                + (P##_001.y * w00 + P##_011.y * w01 + P##_101.y * w10 + P##_111.y * w11) * ww1; \
    }

__global__ __launch_bounds__(256, 4) void st_warp4_kernel(
    const float* __restrict__ vol,
    const float* __restrict__ flow,
    float* __restrict__ out)
{
    const int bid = blockIdx.x;
    const int tid = threadIdx.x;
    const int g   = (bid << 8) + tid;   // group id, 2^21 total
    const int idx = g << 2;             // base voxel

    // block covers 1024 consecutive voxels: b, d uniform; h spans 8 rows
    const int b_s = bid >> 10;          // scalar
    const int d_s = (bid >> 4) & 63;    // scalar
    const int w0  = idx & 127;
    const int h   = (idx >> 7) & 127;

    const float* vb = vol + ((size_t)b_s << 21);  // SGPR base

    // ---- phase 1: flow (48 B contiguous, 6 x float2) + address math ----
    const float2* fp = (const float2*)(flow + (size_t)idx * 3);
    const float2 q0 = fp[0];  // v0.d, v0.h
    const float2 q1 = fp[1];  // v0.w, v1.d
    const float2 q2 = fp[2];  // v1.h, v1.w
    const float2 q3 = fp[3];  // v2.d, v2.h
    const float2 q4 = fp[4];  // v2.w, v3.d
    const float2 q5 = fp[5];  // v3.h, v3.w

    const float fd_ = (float)d_s;
    const float fh_ = (float)h;

    const CornerInfo c0 = mkaddr(fd_ + q0.x, fh_ + q0.y, (float)(w0 + 0) + q1.x);
    const CornerInfo c1 = mkaddr(fd_ + q1.y, fh_ + q2.x, (float)(w0 + 1) + q2.y);
    const CornerInfo c2 = mkaddr(fd_ + q3.x, fh_ + q3.y, (float)(w0 + 2) + q4.x);
    const CornerInfo c3 = mkaddr(fd_ + q4.y, fh_ + q5.x, (float)(w0 + 3) + q5.y);

    // ---- phase 2: all 32 gathers ----
    GATHER8(a, vb, c0.o)
    GATHER8(b, vb, c1.o)
    GATHER8(c, vb, c2.o)
    GATHER8(e, vb, c3.o)

    // ---- phase 3: combine + store ----
    float2 r0, r1, r2, r3;
    COMBINE(a, c0, r0)
    COMBINE(b, c1, r1)
    COMBINE(c, c2, r2)
    COMBINE(e, c3, r3)

    float4* o4 = reinterpret_cast<float4*>(out);
    o4[(size_t)g * 2]     = make_float4(r0.x, r0.y, r1.x, r1.y);
    o4[(size_t)g * 2 + 1] = make_float4(r2.x, r2.y, r3.x, r3.y);
}

extern "C" void kernel_launch(void* const* d_in, const int* in_sizes, int n_in,
                              void* d_out, int out_size, void* d_ws, size_t ws_size,
                              hipStream_t stream) {
    const float* vol  = (const float*)d_in[0];
    const float* flow = (const float*)d_in[1];
    float* out = (float*)d_out;

    const int total   = in_sizes[1] / 3;  // B*D*H*W = 8388608
    const int ngroups = total >> 2;       // 2097152
    const int grid    = ngroups / 256;    // 8192

    hipLaunchKernelGGL(st_warp4_kernel, dim3(grid), dim3(256), 0, stream,
                       vol, flow, out);
}

// Round 6
// 91.434 us; speedup vs baseline: 1.1185x; 1.0247x over previous
//
#include <hip/hip_runtime.h>

// vol:  [B=8, D=64, H=128, W=128, C=2] f32
// flow: [B, D, H, W, 3] f32 (displacements)
// out:  [B, D, H, W, C] f32
//
// 4 consecutive W-voxels per thread, three-phase structure:
//   phase 1: flow loads + all address/weight math (4 voxels)
//   phase 2: all 32 float2 gathers issued together
//   --- sched_barrier(0): loads may not sink, combines may not hoist ---
//   phase 3: weighted combine + 2 x float4 stores
// The barrier forces ~32 loads in flight per wave (VGPR should rise to ~96+).
// b, d are block-uniform -> SGPR volume base, 32-bit per-lane offsets.

struct CornerInfo {
    int   o;   // element offset of (ld,lh,lw) corner within batch volume
    float wd, wh, ww;
};

__device__ __forceinline__ CornerInfo mkaddr(float cd, float ch, float cw) {
    cd = fminf(fmaxf(cd, 0.0f), 63.0f);
    ch = fminf(fmaxf(ch, 0.0f), 127.0f);
    cw = fminf(fmaxf(cw, 0.0f), 127.0f);
    int ld = (int)cd; ld = (ld > 62) ? 62 : ld;
    int lh = (int)ch; lh = (lh > 126) ? 126 : lh;
    int lw = (int)cw; lw = (lw > 126) ? 126 : lw;
    CornerInfo ci;
    ci.o  = (ld << 15) + (lh << 8) + (lw << 1);
    ci.wd = cd - (float)ld;
    ci.wh = ch - (float)lh;
    ci.ww = cw - (float)lw;
    return ci;
}

// 8 corner loads for one voxel: two d-planes, 4 imm-offset float2 loads each
#define GATHER8(P, base, o)                                          \
    const float2 P##_000 = *(const float2*)((base) + (o));           \
    const float2 P##_001 = *(const float2*)((base) + (o) + 2);       \
    const float2 P##_010 = *(const float2*)((base) + (o) + 256);     \
    const float2 P##_011 = *(const float2*)((base) + (o) + 258);     \
    const float2 P##_100 = *(const float2*)((base) + (o) + 32768);   \
    const float2 P##_101 = *(const float2*)((base) + (o) + 32770);   \
    const float2 P##_110 = *(const float2*)((base) + (o) + 33024);   \
    const float2 P##_111 = *(const float2*)((base) + (o) + 33026);

#define COMBINE(P, ci, res)                                                     \
    {                                                                           \
        const float wd0 = 1.0f - (ci).wd, wh0 = 1.0f - (ci).wh;                 \
        const float ww1 = (ci).ww, ww0 = 1.0f - ww1;                            \
        const float w00 = wd0 * wh0, w01 = wd0 * (ci).wh;                       \
        const float w10 = (ci).wd * wh0, w11 = (ci).wd * (ci).wh;               \
        (res).x = (P##_000.x * w00 + P##_010.x * w01 + P##_100.x * w10 + P##_110.x * w11) * ww0  \
                + (P##_001.x * w00 + P##_011.x * w01 + P##_101.x * w10 + P##_111.x * w11) * ww1; \
        (res).y = (P##_000.y * w00 + P##_010.y * w01 + P##_100.y * w10 + P##_110.y * w11) * ww0  \
                + (P##_001.y * w00 + P##_011.y * w01 + P##_101.y * w10 + P##_111.y * w11) * ww1; \
    }

__global__ __launch_bounds__(256, 4) void st_warp4_kernel(
    const float* __restrict__ vol,
    const float* __restrict__ flow,
    float* __restrict__ out)
{
    const int bid = blockIdx.x;
    const int tid = threadIdx.x;
    const int g   = (bid << 8) + tid;   // group id, 2^21 total
    const int idx = g << 2;             // base voxel

    // block covers 1024 consecutive voxels: b, d uniform; h spans 8 rows
    const int b_s = bid >> 10;          // scalar
    const int d_s = (bid >> 4) & 63;    // scalar
    const int w0  = idx & 127;
    const int h   = (idx >> 7) & 127;

    const float* vb = vol + ((size_t)b_s << 21);  // SGPR base

    // ---- phase 1: flow (48 B contiguous, 6 x float2) + address math ----
    const float2* fp = (const float2*)(flow + (size_t)idx * 3);
    const float2 q0 = fp[0];  // v0.d, v0.h
    const float2 q1 = fp[1];  // v0.w, v1.d
    const float2 q2 = fp[2];  // v1.h, v1.w
    const float2 q3 = fp[3];  // v2.d, v2.h
    const float2 q4 = fp[4];  // v2.w, v3.d
    const float2 q5 = fp[5];  // v3.h, v3.w

    const float fd_ = (float)d_s;
    const float fh_ = (float)h;

    const CornerInfo c0 = mkaddr(fd_ + q0.x, fh_ + q0.y, (float)(w0 + 0) + q1.x);
    const CornerInfo c1 = mkaddr(fd_ + q1.y, fh_ + q2.x, (float)(w0 + 1) + q2.y);
    const CornerInfo c2 = mkaddr(fd_ + q3.x, fh_ + q3.y, (float)(w0 + 2) + q4.x);
    const CornerInfo c3 = mkaddr(fd_ + q4.y, fh_ + q5.x, (float)(w0 + 3) + q5.y);

    // ---- phase 2: all 32 gathers, pinned above the barrier ----
    GATHER8(a, vb, c0.o)
    GATHER8(b, vb, c1.o)
    GATHER8(c, vb, c2.o)
    GATHER8(e, vb, c3.o)

    // Scheduling fence: no instruction may cross. Forces all 32 loads to be
    // issued before any combine -> 32-deep per-wave MLP, VGPR ~96+.
    __builtin_amdgcn_sched_barrier(0);

    // ---- phase 3: combine + store ----
    float2 r0, r1, r2, r3;
    COMBINE(a, c0, r0)
    COMBINE(b, c1, r1)
    COMBINE(c, c2, r2)
    COMBINE(e, c3, r3)

    float4* o4 = reinterpret_cast<float4*>(out);
    o4[(size_t)g * 2]     = make_float4(r0.x, r0.y, r1.x, r1.y);
    o4[(size_t)g * 2 + 1] = make_float4(r2.x, r2.y, r3.x, r3.y);
}

extern "C" void kernel_launch(void* const* d_in, const int* in_sizes, int n_in,
                              void* d_out, int out_size, void* d_ws, size_t ws_size,
                              hipStream_t stream) {
    const float* vol  = (const float*)d_in[0];
    const float* flow = (const float*)d_in[1];
    float* out = (float*)d_out;

    const int total   = in_sizes[1] / 3;  // B*D*H*W = 8388608
    const int ngroups = total >> 2;       // 2097152
    const int grid    = ngroups / 256;    // 8192

    hipLaunchKernelGGL(st_warp4_kernel, dim3(grid), dim3(256), 0, stream,
                       vol, flow, out);
}

// Round 7
// 85.166 us; speedup vs baseline: 1.2008x; 1.0736x over previous
//
#include <hip/hip_runtime.h>

// vol:  [B=8, D=64, H=128, W=128, C=2] f32
// flow: [B, D, H, W, 3] f32 (displacements)
// out:  [B, D, H, W, C] f32
//
// 4 consecutive W-voxels per thread. Key change (R7): the two W-corner
// float2s per (d-plane, h-row) are contiguous (4 floats, 8B-aligned) ->
// merged into ONE 16B load. 16 gather instructions/thread instead of 32,
// ~1.6x fewer L1 tag-lookups (the round-6-identified bottleneck).

typedef float f32x4 __attribute__((ext_vector_type(4)));
typedef f32x4 __attribute__((aligned(8))) f32x4a;  // 16B load, 8B-aligned ok

struct CornerInfo {
    int   o;   // element offset of (ld,lh,lw) corner within batch volume
    float wd, wh, ww;
};

__device__ __forceinline__ CornerInfo mkaddr(float cd, float ch, float cw) {
    cd = fminf(fmaxf(cd, 0.0f), 63.0f);
    ch = fminf(fmaxf(ch, 0.0f), 127.0f);
    cw = fminf(fmaxf(cw, 0.0f), 127.0f);
    int ld = (int)cd; ld = (ld > 62) ? 62 : ld;
    int lh = (int)ch; lh = (lh > 126) ? 126 : lh;
    int lw = (int)cw; lw = (lw > 126) ? 126 : lw;
    CornerInfo ci;
    ci.o  = (ld << 15) + (lh << 8) + (lw << 1);
    ci.wd = cd - (float)ld;
    ci.wh = ch - (float)lh;
    ci.ww = cw - (float)lw;
    return ci;
}

// 4 merged 16B loads per voxel: (ld,lh),(ld,lh+1),(ld+1,lh),(ld+1,lh+1)
// each = [c_lw.x, c_lw.y, c_lw1.x, c_lw1.y]
#define GATHER4(P, base, o)                                            \
    const f32x4 P##_00 = *(const f32x4a*)((base) + (o));               \
    const f32x4 P##_01 = *(const f32x4a*)((base) + (o) + 256);         \
    const f32x4 P##_10 = *(const f32x4a*)((base) + (o) + 32768);       \
    const f32x4 P##_11 = *(const f32x4a*)((base) + (o) + 33024);

#define COMBINE(P, ci, res)                                                       \
    {                                                                             \
        const float wd0 = 1.0f - (ci).wd, wh0 = 1.0f - (ci).wh;                   \
        const float ww1 = (ci).ww, ww0 = 1.0f - ww1;                              \
        const float w00 = wd0 * wh0, w01 = wd0 * (ci).wh;                         \
        const float w10 = (ci).wd * wh0, w11 = (ci).wd * (ci).wh;                 \
        (res).x = (P##_00.x * w00 + P##_01.x * w01 + P##_10.x * w10 + P##_11.x * w11) * ww0  \
                + (P##_00.z * w00 + P##_01.z * w01 + P##_10.z * w10 + P##_11.z * w11) * ww1; \
        (res).y = (P##_00.y * w00 + P##_01.y * w01 + P##_10.y * w10 + P##_11.y * w11) * ww0  \
                + (P##_00.w * w00 + P##_01.w * w01 + P##_10.w * w10 + P##_11.w * w11) * ww1; \
    }

__global__ __launch_bounds__(256, 4) void st_warp4_kernel(
    const float* __restrict__ vol,
    const float* __restrict__ flow,
    float* __restrict__ out)
{
    const int bid = blockIdx.x;
    const int tid = threadIdx.x;
    const int g   = (bid << 8) + tid;   // group id, 2^21 total
    const int idx = g << 2;             // base voxel

    // block covers 1024 consecutive voxels: b, d uniform; h spans 8 rows
    const int b_s = bid >> 10;          // scalar
    const int d_s = (bid >> 4) & 63;    // scalar
    const int w0  = idx & 127;
    const int h   = (idx >> 7) & 127;

    const float* vb = vol + ((size_t)b_s << 21);  // SGPR base

    // ---- phase 1: flow (48 B contiguous, 6 x float2) + address math ----
    const float2* fp = (const float2*)(flow + (size_t)idx * 3);
    const float2 q0 = fp[0];  // v0.d, v0.h
    const float2 q1 = fp[1];  // v0.w, v1.d
    const float2 q2 = fp[2];  // v1.h, v1.w
    const float2 q3 = fp[3];  // v2.d, v2.h
    const float2 q4 = fp[4];  // v2.w, v3.d
    const float2 q5 = fp[5];  // v3.h, v3.w

    const float fd_ = (float)d_s;
    const float fh_ = (float)h;

    const CornerInfo c0 = mkaddr(fd_ + q0.x, fh_ + q0.y, (float)(w0 + 0) + q1.x);
    const CornerInfo c1 = mkaddr(fd_ + q1.y, fh_ + q2.x, (float)(w0 + 1) + q2.y);
    const CornerInfo c2 = mkaddr(fd_ + q3.x, fh_ + q3.y, (float)(w0 + 2) + q4.x);
    const CornerInfo c3 = mkaddr(fd_ + q4.y, fh_ + q5.x, (float)(w0 + 3) + q5.y);

    // ---- phase 2: all 16 merged gathers, pinned above the barrier ----
    GATHER4(a, vb, c0.o)
    GATHER4(b, vb, c1.o)
    GATHER4(c, vb, c2.o)
    GATHER4(e, vb, c3.o)

    __builtin_amdgcn_sched_barrier(0);

    // ---- phase 3: combine + store ----
    float2 r0, r1, r2, r3;
    COMBINE(a, c0, r0)
    COMBINE(b, c1, r1)
    COMBINE(c, c2, r2)
    COMBINE(e, c3, r3)

    float4* o4 = reinterpret_cast<float4*>(out);
    o4[(size_t)g * 2]     = make_float4(r0.x, r0.y, r1.x, r1.y);
    o4[(size_t)g * 2 + 1] = make_float4(r2.x, r2.y, r3.x, r3.y);
}

extern "C" void kernel_launch(void* const* d_in, const int* in_sizes, int n_in,
                              void* d_out, int out_size, void* d_ws, size_t ws_size,
                              hipStream_t stream) {
    const float* vol  = (const float*)d_in[0];
    const float* flow = (const float*)d_in[1];
    float* out = (float*)d_out;

    const int total   = in_sizes[1] / 3;  // B*D*H*W = 8388608
    const int ngroups = total >> 2;       // 2097152
    const int grid    = ngroups / 256;    // 8192

    hipLaunchKernelGGL(st_warp4_kernel, dim3(grid), dim3(256), 0, stream,
                       vol, flow, out);
}

// Round 10
// 81.467 us; speedup vs baseline: 1.2553x; 1.0454x over previous
//
#include <hip/hip_runtime.h>

// vol:  [B=8, D=64, H=128, W=128, C=2] f32
// flow: [B, D, H, W, 3] f32 (displacements)
// out:  [B, D, H, W, C] f32
//
// R10: LDS-staged tile gather (R9 + staging index fix: 64 f32x4/row, not 16).
//  - block = 1024 threads -> 4(d) x 4(h) x 128(w) output voxels (2048),
//    2 voxels/thread. 1 block/CU (LDS-bound), 16 waves/CU.
//  - stage vol planes [d0-4,d0+7] x rows [h0-4,h0+7]: 144 rows x 256 floats,
//    LDS row stride 260 (16B-aligned rows + 4-bank rotation per row).
//  - each wave: uniform (d,h) row, lanes = 64 consecutive W -> coalesced
//    flow loads + out stores; LDS gathers eat the +-2 jitter at 32 banks.
//  - |jitter| > ~4 planes/rows (P ~ 1e-4): exec-masked global fallback.

typedef float f32x4 __attribute__((ext_vector_type(4)));
typedef f32x4 __attribute__((aligned(8))) f32x4a;  // 16B global load, 8B-aligned

#define RSTRIDE 260
#define NROWS   144   // 12 x 12 (d,h) row-slots

__global__ __launch_bounds__(1024) void st_tile_kernel(
    const float* __restrict__ vol,
    const float* __restrict__ flow,
    float* __restrict__ out)
{
    __shared__ float lds[NROWS * RSTRIDE];   // 149,760 B static

    const int t   = threadIdx.x;
    const int bid = blockIdx.x;

    // bid -> (b, d-tile, h-tile); h fastest so neighbor blocks share planes
    const int h0 = (bid & 31) << 2;
    const int d0 = ((bid >> 5) & 15) << 2;
    const int b  = bid >> 9;

    const int dbase = d0 - 4;
    const int hbase = h0 - 4;

    const float* vb = vol + ((size_t)b << 21);  // batch base, 2^21 floats

    // ---- stage: 144 rows x 64 f32x4-chunks = 9216 chunks, 1024 threads ----
    for (int c = t; c < NROWS * 64; c += 1024) {
        const int s = c >> 6, q = c & 63;            // s: row-slot, q: f32x4 chunk
        const int i_d = s / 12, i_h = s - i_d * 12;
        const int gd = min(max(dbase + i_d, 0), 63);
        const int gh = min(max(hbase + i_h, 0), 127);
        const f32x4* src = (const f32x4*)(vb + ((((size_t)gd << 7) + gh) << 8));
        *(f32x4*)&lds[s * RSTRIDE + (q << 2)] = src[q];
    }
    __syncthreads();

    // ---- gather: 2 voxels per thread; wave-uniform (d,h) row ----
    const int iw = t & 63;
    const int r  = t >> 6;            // 0..15, uniform per wave
    const int d  = d0 + (r >> 2);
    const int h  = h0 + (r & 3);

    const float fd_ = (float)d, fh_ = (float)h;
    const size_t rowbase = ((((size_t)((b << 6) | d) << 7) | h) << 7);  // voxel idx @ w=0

#pragma unroll
    for (int k = 0; k < 2; ++k) {
        const int w = iw + (k << 6);
        const size_t idx = rowbase + w;
        const float* fpp = flow + idx * 3;
        const float f0 = fpp[0], f1 = fpp[1], f2 = fpp[2];

        float cd = fminf(fmaxf(fd_ + f0, 0.0f), 63.0f);
        float ch = fminf(fmaxf(fh_ + f1, 0.0f), 127.0f);
        float cw = fminf(fmaxf((float)w + f2, 0.0f), 127.0f);

        int ld = (int)cd; ld = (ld > 62) ? 62 : ld;
        int lh = (int)ch; lh = (lh > 126) ? 126 : lh;
        int lw = (int)cw; lw = (lw > 126) ? 126 : lw;

        const float wd = cd - (float)ld;
        const float wh = ch - (float)lh;
        const float ww = cw - (float)lw;

        const int i_d = ld - dbase;
        const int i_h = lh - hbase;

        float2 p00l, p00r, p01l, p01r, p10l, p10r, p11l, p11r;
        if (__builtin_expect(((unsigned)i_d <= 10u) & ((unsigned)i_h <= 10u), 1)) {
            const int e = (i_d * 12 + i_h) * RSTRIDE + (lw << 1);
            p00l = *(const float2*)&lds[e];
            p00r = *(const float2*)&lds[e + 2];
            p01l = *(const float2*)&lds[e + RSTRIDE];
            p01r = *(const float2*)&lds[e + RSTRIDE + 2];
            p10l = *(const float2*)&lds[e + 12 * RSTRIDE];
            p10r = *(const float2*)&lds[e + 12 * RSTRIDE + 2];
            p11l = *(const float2*)&lds[e + 13 * RSTRIDE];
            p11r = *(const float2*)&lds[e + 13 * RSTRIDE + 2];
        } else {
            const int o = (ld << 15) + (lh << 8) + (lw << 1);
            const f32x4 a00 = *(const f32x4a*)(vb + o);
            const f32x4 a01 = *(const f32x4a*)(vb + o + 256);
            const f32x4 a10 = *(const f32x4a*)(vb + o + 32768);
            const f32x4 a11 = *(const f32x4a*)(vb + o + 33024);
            p00l = make_float2(a00.x, a00.y); p00r = make_float2(a00.z, a00.w);
            p01l = make_float2(a01.x, a01.y); p01r = make_float2(a01.z, a01.w);
            p10l = make_float2(a10.x, a10.y); p10r = make_float2(a10.z, a10.w);
            p11l = make_float2(a11.x, a11.y); p11r = make_float2(a11.z, a11.w);
        }

        const float wd0 = 1.0f - wd, wh0 = 1.0f - wh;
        const float ww1 = ww, ww0 = 1.0f - ww;
        const float w00 = wd0 * wh0, w01 = wd0 * wh;
        const float w10 = wd * wh0,  w11 = wd * wh;

        const float ox = (p00l.x * w00 + p01l.x * w01 + p10l.x * w10 + p11l.x * w11) * ww0
                       + (p00r.x * w00 + p01r.x * w01 + p10r.x * w10 + p11r.x * w11) * ww1;
        const float oy = (p00l.y * w00 + p01l.y * w01 + p10l.y * w10 + p11l.y * w11) * ww0
                       + (p00r.y * w00 + p01r.y * w01 + p10r.y * w10 + p11r.y * w11) * ww1;

        *(float2*)(out + idx * 2) = make_float2(ox, oy);
    }
}

extern "C" void kernel_launch(void* const* d_in, const int* in_sizes, int n_in,
                              void* d_out, int out_size, void* d_ws, size_t ws_size,
                              hipStream_t stream) {
    const float* vol  = (const float*)d_in[0];
    const float* flow = (const float*)d_in[1];
    float* out = (float*)d_out;

    // 8 batches x 16 d-tiles x 32 h-tiles = 4096 blocks, 1024 threads each
    hipLaunchKernelGGL(st_tile_kernel, dim3(4096), dim3(1024), 0, stream,
                       vol, flow, out);
}

// Round 11
// 65.304 us; speedup vs baseline: 1.5660x; 1.2475x over previous
//
#include <hip/hip_runtime.h>

// vol:  [B=8, D=64, H=128, W=128, C=2] f32
// flow: [B, D, H, W, 3] f32 (displacements)
// out:  [B, D, H, W, C] f32
//
// R11: persistent rolling-window LDS gather.
//  - 256 blocks (8 b x 32 h-tiles) x 1024 threads, 1 per CU; each block
//    walks 16 d-tiles (d0 = 0,4,...,60).
//  - LDS: circular 12-plane window, slot = plane mod 12; each slot =
//    12 h-rows x 260 floats (stride-260: 16B rows + bank rotation).
//  - per iter: stage only 4 new planes (48 rows, 3 f32x4/thread) into the
//    4 vacated slots; prefetch staged chunks + next flow at TOP of iter
//    (sched_barrier-pinned) so they fly during the gather phase (T14).
//  - gather: 2 voxels/thread, wave-uniform (d,h), lanes = 64 consecutive W.
//  - |jitter| > ~4 planes/rows (P~1e-4): exec-masked global fallback.

typedef float f32x4 __attribute__((ext_vector_type(4)));
typedef f32x4 __attribute__((aligned(8))) f32x4a;

#define RSTRIDE 260
#define PLANE   (12 * RSTRIDE)    // floats per d-slot (12 rows)
#define NSLOT   12

__device__ __forceinline__ void sample_store(
    const float* __restrict__ vb, const float* lds,
    float f0, float f1, float f2,
    int d, int h, int w, int dbase, int hbase,
    float* __restrict__ out, size_t idx)
{
    float cd = fminf(fmaxf((float)d + f0, 0.0f), 63.0f);
    float ch = fminf(fmaxf((float)h + f1, 0.0f), 127.0f);
    float cw = fminf(fmaxf((float)w + f2, 0.0f), 127.0f);
    int ld = (int)cd; ld = (ld > 62) ? 62 : ld;
    int lh = (int)ch; lh = (lh > 126) ? 126 : lh;
    int lw = (int)cw; lw = (lw > 126) ? 126 : lw;
    const float wd = cd - (float)ld;
    const float wh = ch - (float)lh;
    const float ww = cw - (float)lw;
    const int i_d = ld - dbase;
    const int i_h = lh - hbase;

    float2 p00l, p00r, p01l, p01r, p10l, p10r, p11l, p11r;
    if (__builtin_expect(((unsigned)i_d <= 10u) & ((unsigned)i_h <= 10u), 1)) {
        int m0 = ld % 12;
        int m1 = m0 + 1; m1 = (m1 == 12) ? 0 : m1;
        const int eA = m0 * PLANE + i_h * RSTRIDE + (lw << 1);
        const int eB = m1 * PLANE + i_h * RSTRIDE + (lw << 1);
        p00l = *(const float2*)&lds[eA];
        p00r = *(const float2*)&lds[eA + 2];
        p01l = *(const float2*)&lds[eA + RSTRIDE];
        p01r = *(const float2*)&lds[eA + RSTRIDE + 2];
        p10l = *(const float2*)&lds[eB];
        p10r = *(const float2*)&lds[eB + 2];
        p11l = *(const float2*)&lds[eB + RSTRIDE];
        p11r = *(const float2*)&lds[eB + RSTRIDE + 2];
    } else {
        const int o = (ld << 15) + (lh << 8) + (lw << 1);
        const f32x4 a00 = *(const f32x4a*)(vb + o);
        const f32x4 a01 = *(const f32x4a*)(vb + o + 256);
        const f32x4 a10 = *(const f32x4a*)(vb + o + 32768);
        const f32x4 a11 = *(const f32x4a*)(vb + o + 33024);
        p00l = make_float2(a00.x, a00.y); p00r = make_float2(a00.z, a00.w);
        p01l = make_float2(a01.x, a01.y); p01r = make_float2(a01.z, a01.w);
        p10l = make_float2(a10.x, a10.y); p10r = make_float2(a10.z, a10.w);
        p11l = make_float2(a11.x, a11.y); p11r = make_float2(a11.z, a11.w);
    }

    const float wd0 = 1.0f - wd, wh0 = 1.0f - wh;
    const float ww1 = ww, ww0 = 1.0f - ww;
    const float w00 = wd0 * wh0, w01 = wd0 * wh;
    const float w10 = wd * wh0,  w11 = wd * wh;

    const float ox = (p00l.x * w00 + p01l.x * w01 + p10l.x * w10 + p11l.x * w11) * ww0
                   + (p00r.x * w00 + p01r.x * w01 + p10r.x * w10 + p11r.x * w11) * ww1;
    const float oy = (p00l.y * w00 + p01l.y * w01 + p10l.y * w10 + p11l.y * w11) * ww0
                   + (p00r.y * w00 + p01r.y * w01 + p10r.y * w10 + p11r.y * w11) * ww1;

    *(float2*)(out + idx * 2) = make_float2(ox, oy);
}

__global__ __launch_bounds__(1024, 4) void st_roll_kernel(
    const float* __restrict__ vol,
    const float* __restrict__ flow,
    float* __restrict__ out)
{
    __shared__ float lds[NSLOT * PLANE];   // 149,760 B

    const int t   = threadIdx.x;
    const int bid = blockIdx.x;            // b*32 + htile
    const int h0    = (bid & 31) << 2;
    const int b     = bid >> 5;
    const int hbase = h0 - 4;

    const float* vb = vol + ((size_t)b << 21);

    // gather identity: wave-uniform (d-offset, h); lanes span 64 W
    const int iw = t & 63;
    const int r  = t >> 6;          // 0..15
    const int dr = r >> 2;          // 0..3: d offset within tile
    const int hh = h0 + (r & 3);    // output h row (fixed across iters)

    // ---- initial stage: planes [-4..7] -> slots (i_d+8)%12 (144 rows) ----
    {
        f32x4 v0, v1, v2, v3, v4, v5, v6, v7, v8;
        int   e0, e1, e2, e3, e4, e5, e6, e7, e8;
#define ISSUE_INIT(K, VV, EE)                                                    \
        {                                                                        \
            const int c = t + (K) * 1024;                                        \
            const int s = c >> 6, q = c & 63;                                    \
            const int i_d = s / 12, i_h = s - i_d * 12;                          \
            const int gd = max(i_d - 4, 0);                                      \
            const int gh = min(max(hbase + i_h, 0), 127);                        \
            VV = *(const f32x4*)(vb + ((((size_t)gd << 7) + gh) << 8) + (q << 2)); \
            EE = ((i_d + 8) % 12) * PLANE + i_h * RSTRIDE + (q << 2);            \
        }
        ISSUE_INIT(0, v0, e0) ISSUE_INIT(1, v1, e1) ISSUE_INIT(2, v2, e2)
        ISSUE_INIT(3, v3, e3) ISSUE_INIT(4, v4, e4) ISSUE_INIT(5, v5, e5)
        ISSUE_INIT(6, v6, e6) ISSUE_INIT(7, v7, e7) ISSUE_INIT(8, v8, e8)
#undef ISSUE_INIT
        *(f32x4*)&lds[e0] = v0; *(f32x4*)&lds[e1] = v1; *(f32x4*)&lds[e2] = v2;
        *(f32x4*)&lds[e3] = v3; *(f32x4*)&lds[e4] = v4; *(f32x4*)&lds[e5] = v5;
        *(f32x4*)&lds[e6] = v6; *(f32x4*)&lds[e7] = v7; *(f32x4*)&lds[e8] = v8;
    }

    // prologue: flow for dt=0
    float cfA0, cfA1, cfA2, cfB0, cfB1, cfB2;
    {
        const int d = dr;
        const size_t rowbase = ((((size_t)((b << 6) | d) << 7) | hh) << 7);
        const float* fA = flow + (rowbase + iw) * 3;
        cfA0 = fA[0]; cfA1 = fA[1]; cfA2 = fA[2];
        const float* fB = flow + (rowbase + iw + 64) * 3;
        cfB0 = fB[0]; cfB1 = fB[1]; cfB2 = fB[2];
    }
    __syncthreads();

    for (int dt = 0; dt < 16; ++dt) {
        const int d0    = dt << 2;
        const int dbase = d0 - 4;
        const int d     = d0 + dr;
        const size_t rowbase = ((((size_t)((b << 6) | d) << 7) | hh) << 7);
        const size_t idxA = rowbase + iw;

        // ---- prefetch next-iter staging (3 f32x4) + flow (6 f32) ----
        f32x4 s0, s1, s2;
        int   le0, le1, le2;
        float nfA0, nfA1, nfA2, nfB0, nfB1, nfB2;
        if (dt < 15) {
            const int dbn = d0;   // next window base
#define ISSUE_ST(K, VV, EE)                                                      \
            {                                                                    \
                const int c = t + (K) * 1024;                                    \
                const int row = c >> 6, q = c & 63;                              \
                const int i_d4 = row / 12, i_h = row - i_d4 * 12;                \
                const int p  = dbn + 8 + i_d4;                                   \
                const int gd = min(p, 63);                                       \
                const int gh = min(max(hbase + i_h, 0), 127);                    \
                VV = *(const f32x4*)(vb + ((((size_t)gd << 7) + gh) << 8) + (q << 2)); \
                EE = (p % 12) * PLANE + i_h * RSTRIDE + (q << 2);                \
            }
            ISSUE_ST(0, s0, le0) ISSUE_ST(1, s1, le1) ISSUE_ST(2, s2, le2)
#undef ISSUE_ST
            const int dn = d0 + 4 + dr;
            const size_t rbn = ((((size_t)((b << 6) | dn) << 7) | hh) << 7);
            const float* fA = flow + (rbn + iw) * 3;
            nfA0 = fA[0]; nfA1 = fA[1]; nfA2 = fA[2];
            const float* fB = flow + (rbn + iw + 64) * 3;
            nfB0 = fB[0]; nfB1 = fB[1]; nfB2 = fB[2];
            __builtin_amdgcn_sched_barrier(0);   // pin prefetch above gather
        }

        // ---- gather current tile (reads LDS window + rare global) ----
        sample_store(vb, lds, cfA0, cfA1, cfA2, d, hh, iw,      dbase, hbase, out, idxA);
        sample_store(vb, lds, cfB0, cfB1, cfB2, d, hh, iw + 64, dbase, hbase, out, idxA + 64);

        // ---- rotate window: overwrite the 4 vacated slots ----
        if (dt < 15) {
            __syncthreads();                    // all gathers done
            *(f32x4*)&lds[le0] = s0;
            *(f32x4*)&lds[le1] = s1;
            *(f32x4*)&lds[le2] = s2;
            __syncthreads();                    // new planes visible
            cfA0 = nfA0; cfA1 = nfA1; cfA2 = nfA2;
            cfB0 = nfB0; cfB1 = nfB1; cfB2 = nfB2;
        }
    }
}

extern "C" void kernel_launch(void* const* d_in, const int* in_sizes, int n_in,
                              void* d_out, int out_size, void* d_ws, size_t ws_size,
                              hipStream_t stream) {
    const float* vol  = (const float*)d_in[0];
    const float* flow = (const float*)d_in[1];
    float* out = (float*)d_out;

    // 8 batches x 32 h-tiles = 256 persistent blocks (1 per CU)
    hipLaunchKernelGGL(st_roll_kernel, dim3(256), dim3(1024), 0, stream,
                       vol, flow, out);
}

// Round 12
// 65.131 us; speedup vs baseline: 1.5702x; 1.0026x over previous
//
#include <hip/hip_runtime.h>

// vol:  [B=8, D=64, H=128, W=128, C=2] f32
// flow: [B, D, H, W, 3] f32 (displacements)
// out:  [B, D, H, W, C] f32
//
// R12 = R11 (persistent rolling-window) + channel-split LDS layout:
//  - LDS: x-channel and y-channel arrays, each [12 planes][12 rows][130],
//    total 149,760 B (same as R11). Gather reads are b32 at offset lw with
//    lanes on 64 consecutive w -> 2 lanes/bank = conflict-FREE (vs 4-way
//    even-parity aliasing of the interleaved float2 layout, m136).
//    Adjacent offsets {0,1,130,131} -> compiler merges to ds_read2_b32.
//  - slot math scalar-ized: db12 = dbase mod 12 carried incrementally.
//  - otherwise identical: 256 blocks x 1024 thr, 16 d-tiles/block,
//    4-plane rolling stage prefetched at top of iter (sched_barrier-pinned).

typedef float f32x4 __attribute__((ext_vector_type(4)));
typedef f32x4 __attribute__((aligned(8))) f32x4a;

#define HSTRIDE 130               // floats per row per channel (128 + 2 pad)
#define PLANE_C (12 * HSTRIDE)    // 1560 floats: one d-slot, one channel
#define CHOFF   (12 * PLANE_C)    // 18720: y-channel offset
#define NSLOT   12

__device__ __forceinline__ void sample_store(
    const float* __restrict__ vb, const float* lds, int db12,
    float f0, float f1, float f2,
    int d, int h, int w, int dbase, int hbase,
    float* __restrict__ out, size_t idx)
{
    float cd = fminf(fmaxf((float)d + f0, 0.0f), 63.0f);
    float ch = fminf(fmaxf((float)h + f1, 0.0f), 127.0f);
    float cw = fminf(fmaxf((float)w + f2, 0.0f), 127.0f);
    int ld = (int)cd; ld = (ld > 62) ? 62 : ld;
    int lh = (int)ch; lh = (lh > 126) ? 126 : lh;
    int lw = (int)cw; lw = (lw > 126) ? 126 : lw;
    const float wd = cd - (float)ld;
    const float wh = ch - (float)lh;
    const float ww = cw - (float)lw;
    const int i_d = ld - dbase;
    const int i_h = lh - hbase;

    float x00, x00r, x01, x01r, x10, x10r, x11, x11r;
    float y00, y00r, y01, y01r, y10, y10r, y11, y11r;
    if (__builtin_expect(((unsigned)i_d <= 10u) & ((unsigned)i_h <= 10u), 1)) {
        int m0 = db12 + i_d; if (m0 >= 12) m0 -= 12;
        int m1 = m0 + 1;     if (m1 == 12) m1 = 0;
        const int ex0 = m0 * PLANE_C + i_h * HSTRIDE + lw;   // plane m0, ch x
        const int ex1 = m1 * PLANE_C + i_h * HSTRIDE + lw;   // plane m1, ch x
        x00 = lds[ex0];           x00r = lds[ex0 + 1];
        x01 = lds[ex0 + HSTRIDE]; x01r = lds[ex0 + HSTRIDE + 1];
        x10 = lds[ex1];           x10r = lds[ex1 + 1];
        x11 = lds[ex1 + HSTRIDE]; x11r = lds[ex1 + HSTRIDE + 1];
        y00 = lds[ex0 + CHOFF];           y00r = lds[ex0 + CHOFF + 1];
        y01 = lds[ex0 + CHOFF + HSTRIDE]; y01r = lds[ex0 + CHOFF + HSTRIDE + 1];
        y10 = lds[ex1 + CHOFF];           y10r = lds[ex1 + CHOFF + 1];
        y11 = lds[ex1 + CHOFF + HSTRIDE]; y11r = lds[ex1 + CHOFF + HSTRIDE + 1];
    } else {
        const int o = (ld << 15) + (lh << 8) + (lw << 1);
        const f32x4 a00 = *(const f32x4a*)(vb + o);
        const f32x4 a01 = *(const f32x4a*)(vb + o + 256);
        const f32x4 a10 = *(const f32x4a*)(vb + o + 32768);
        const f32x4 a11 = *(const f32x4a*)(vb + o + 33024);
        x00 = a00.x; y00 = a00.y; x00r = a00.z; y00r = a00.w;
        x01 = a01.x; y01 = a01.y; x01r = a01.z; y01r = a01.w;
        x10 = a10.x; y10 = a10.y; x10r = a10.z; y10r = a10.w;
        x11 = a11.x; y11 = a11.y; x11r = a11.z; y11r = a11.w;
    }

    const float wd0 = 1.0f - wd, wh0 = 1.0f - wh;
    const float ww1 = ww, ww0 = 1.0f - ww;
    const float w00 = wd0 * wh0, w01 = wd0 * wh;
    const float w10 = wd * wh0,  w11 = wd * wh;

    const float ox = (x00 * w00 + x01 * w01 + x10 * w10 + x11 * w11) * ww0
                   + (x00r * w00 + x01r * w01 + x10r * w10 + x11r * w11) * ww1;
    const float oy = (y00 * w00 + y01 * w01 + y10 * w10 + y11 * w11) * ww0
                   + (y00r * w00 + y01r * w01 + y10r * w10 + y11r * w11) * ww1;

    *(float2*)(out + idx * 2) = make_float2(ox, oy);
}

__global__ __launch_bounds__(1024, 4) void st_roll_kernel(
    const float* __restrict__ vol,
    const float* __restrict__ flow,
    float* __restrict__ out)
{
    __shared__ float lds[2 * NSLOT * PLANE_C];   // 149,760 B

    const int t   = threadIdx.x;
    const int bid = blockIdx.x;            // b*32 + htile
    const int h0    = (bid & 31) << 2;
    const int b     = bid >> 5;
    const int hbase = h0 - 4;

    const float* vb = vol + ((size_t)b << 21);

    // gather identity: wave-uniform (d-offset, h); lanes span 64 W
    const int iw = t & 63;
    const int r  = t >> 6;          // 0..15
    const int dr = r >> 2;          // 0..3: d offset within tile
    const int hh = h0 + (r & 3);    // output h row (fixed across iters)

    // ---- initial stage: planes [-4..7] -> slots (i_d+8)%12 (144 rows) ----
    {
        f32x4 v0, v1, v2, v3, v4, v5, v6, v7, v8;
        int   e0, e1, e2, e3, e4, e5, e6, e7, e8;
#define ISSUE_INIT(K, VV, EE)                                                    \
        {                                                                        \
            const int c = t + (K) * 1024;                                        \
            const int s = c >> 6, q = c & 63;                                    \
            const int i_d = s / 12, i_h = s - i_d * 12;                          \
            const int gd = max(i_d - 4, 0);                                      \
            const int gh = min(max(hbase + i_h, 0), 127);                        \
            VV = *(const f32x4*)(vb + ((((size_t)gd << 7) + gh) << 8) + (q << 2)); \
            EE = ((i_d + 8) % 12) * PLANE_C + i_h * HSTRIDE + (q << 1);          \
        }
        ISSUE_INIT(0, v0, e0) ISSUE_INIT(1, v1, e1) ISSUE_INIT(2, v2, e2)
        ISSUE_INIT(3, v3, e3) ISSUE_INIT(4, v4, e4) ISSUE_INIT(5, v5, e5)
        ISSUE_INIT(6, v6, e6) ISSUE_INIT(7, v7, e7) ISSUE_INIT(8, v8, e8)
#undef ISSUE_INIT
#define WR2(VV, EE)                                                              \
        *(float2*)&lds[EE] = make_float2(VV.x, VV.z);                            \
        *(float2*)&lds[EE + CHOFF] = make_float2(VV.y, VV.w);
        WR2(v0, e0) WR2(v1, e1) WR2(v2, e2) WR2(v3, e3) WR2(v4, e4)
        WR2(v5, e5) WR2(v6, e6) WR2(v7, e7) WR2(v8, e8)
#undef WR2
    }

    // prologue: flow for dt=0
    float cfA0, cfA1, cfA2, cfB0, cfB1, cfB2;
    {
        const int d = dr;
        const size_t rowbase = ((((size_t)((b << 6) | d) << 7) | hh) << 7);
        const float* fA = flow + (rowbase + iw) * 3;
        cfA0 = fA[0]; cfA1 = fA[1]; cfA2 = fA[2];
        const float* fB = flow + (rowbase + iw + 64) * 3;
        cfB0 = fB[0]; cfB1 = fB[1]; cfB2 = fB[2];
    }
    __syncthreads();

    int db12 = 8;   // (dbase mod 12) for dt=0 (dbase = -4)
    for (int dt = 0; dt < 16; ++dt) {
        const int d0    = dt << 2;
        const int dbase = d0 - 4;
        const int d     = d0 + dr;
        const size_t rowbase = ((((size_t)((b << 6) | d) << 7) | hh) << 7);
        const size_t idxA = rowbase + iw;

        // ---- prefetch next-iter staging (3 f32x4) + flow (6 f32) ----
        f32x4 s0, s1, s2;
        int   le0, le1, le2;
        float nfA0, nfA1, nfA2, nfB0, nfB1, nfB2;
        if (dt < 15) {
#define ISSUE_ST(K, VV, EE)                                                      \
            {                                                                    \
                const int c = t + (K) * 1024;                                    \
                const int row = c >> 6, q = c & 63;                              \
                const int i_d4 = row / 12, i_h = row - i_d4 * 12;                \
                const int p  = d0 + 8 + i_d4;      /* new planes d0+8..d0+11 */ \
                const int gd = min(p, 63);                                       \
                const int gh = min(max(hbase + i_h, 0), 127);                    \
                VV = *(const f32x4*)(vb + ((((size_t)gd << 7) + gh) << 8) + (q << 2)); \
                int sl = db12 + i_d4; if (sl >= 12) sl -= 12;  /* p mod 12 */    \
                EE = sl * PLANE_C + i_h * HSTRIDE + (q << 1);                    \
            }
            ISSUE_ST(0, s0, le0) ISSUE_ST(1, s1, le1) ISSUE_ST(2, s2, le2)
#undef ISSUE_ST
            const int dn = d0 + 4 + dr;
            const size_t rbn = ((((size_t)((b << 6) | dn) << 7) | hh) << 7);
            const float* fA = flow + (rbn + iw) * 3;
            nfA0 = fA[0]; nfA1 = fA[1]; nfA2 = fA[2];
            const float* fB = flow + (rbn + iw + 64) * 3;
            nfB0 = fB[0]; nfB1 = fB[1]; nfB2 = fB[2];
            __builtin_amdgcn_sched_barrier(0);   // pin prefetch above gather
        }

        // ---- gather current tile (reads LDS window + rare global) ----
        sample_store(vb, lds, db12, cfA0, cfA1, cfA2, d, hh, iw,      dbase, hbase, out, idxA);
        sample_store(vb, lds, db12, cfB0, cfB1, cfB2, d, hh, iw + 64, dbase, hbase, out, idxA + 64);

        // ---- rotate window: overwrite the 4 vacated slots ----
        if (dt < 15) {
            __syncthreads();                    // all gathers done
            *(float2*)&lds[le0] = make_float2(s0.x, s0.z);
            *(float2*)&lds[le0 + CHOFF] = make_float2(s0.y, s0.w);
            *(float2*)&lds[le1] = make_float2(s1.x, s1.z);
            *(float2*)&lds[le1 + CHOFF] = make_float2(s1.y, s1.w);
            *(float2*)&lds[le2] = make_float2(s2.x, s2.z);
            *(float2*)&lds[le2 + CHOFF] = make_float2(s2.y, s2.w);
            __syncthreads();                    // new planes visible
            cfA0 = nfA0; cfA1 = nfA1; cfA2 = nfA2;
            cfB0 = nfB0; cfB1 = nfB1; cfB2 = nfB2;
            db12 += 4; if (db12 >= 12) db12 -= 12;
        }
    }
}

extern "C" void kernel_launch(void* const* d_in, const int* in_sizes, int n_in,
                              void* d_out, int out_size, void* d_ws, size_t ws_size,
                              hipStream_t stream) {
    const float* vol  = (const float*)d_in[0];
    const float* flow = (const float*)d_in[1];
    float* out = (float*)d_out;

    // 8 batches x 32 h-tiles = 256 persistent blocks (1 per CU)
    hipLaunchKernelGGL(st_roll_kernel, dim3(256), dim3(1024), 0, stream,
                       vol, flow, out);
}